// Round 22
// baseline (154.719 us; speedup 1.0000x reference)
//
#include <hip/hip_runtime.h>

// EdgeWeightPredictor: 2-layer GCN (sym-norm, self-loops) + edge MLP.
// N=100000 nodes (IN_CH=6), E=1600000 edges (EDGE_FEAT=8).
// Round 22 (from R21 @ 142.8us): eattr pre-converted to bf16 (25.6MB)
// via grid-stride loop fused into k_bhist (atomic-bound, spare BW).
// k_edge_mfma reads one uint4/edge (half bytes, no pk conversions).
// Identical rounding -> absmax unchanged.

constexpr int TPB = 256;
constexpr int NB = 256;         // level-1 blocks
constexpr int BSH = 8;          // 256 nodes per bucket
constexpr int MAXB = 1024;      // max buckets supported (N <= 262144)

using short8  = __attribute__((ext_vector_type(8))) short;
using f32x16  = __attribute__((ext_vector_type(16))) float;
using uintx4  = __attribute__((ext_vector_type(4))) unsigned;
using floatx4 = __attribute__((ext_vector_type(4))) float;

__device__ __forceinline__ float4 nt_load_f4(const float4* p) {
    floatx4 e = __builtin_nontemporal_load(reinterpret_cast<const floatx4*>(p));
    return float4{e.x, e.y, e.z, e.w};
}
__device__ __forceinline__ uint4 nt_load_u4(const uint4* p) {
    uintx4 e = __builtin_nontemporal_load(reinterpret_cast<const uintx4*>(p));
    return uint4{e.x, e.y, e.z, e.w};
}
__device__ __forceinline__ void nt_store_u4(uint4 v, uint4* p) {
    uintx4 e = {v.x, v.y, v.z, v.w};
    __builtin_nontemporal_store(e, reinterpret_cast<uintx4*>(p));
}

// ---- bf16 pack/unpack (RTNE) ----------------------------------------------
__device__ __forceinline__ float bf_lo(unsigned w) {
    return __builtin_bit_cast(float, (unsigned)(w << 16));
}
__device__ __forceinline__ float bf_hi(unsigned w) {
    return __builtin_bit_cast(float, w & 0xFFFF0000u);
}
__device__ __forceinline__ unsigned bf1(float f) {
    unsigned u = __builtin_bit_cast(unsigned, f);
    return (u + 0x7FFFu + ((u >> 16) & 1u)) >> 16;
}
__device__ __forceinline__ unsigned pk(float lo, float hi) {
    return bf1(lo) | (bf1(hi) << 16);
}
__device__ __forceinline__ void unp8(uint4 v, float* o) {
    o[0] = bf_lo(v.x); o[1] = bf_hi(v.x); o[2] = bf_lo(v.y); o[3] = bf_hi(v.y);
    o[4] = bf_lo(v.z); o[5] = bf_hi(v.z); o[6] = bf_lo(v.w); o[7] = bf_hi(v.w);
}
__device__ __forceinline__ void unp6(uint4 v, float* o) {
    o[0] = bf_lo(v.x); o[1] = bf_hi(v.x); o[2] = bf_lo(v.y); o[3] = bf_hi(v.y);
    o[4] = bf_lo(v.z); o[5] = bf_hi(v.z);
}

// ---- level-1 histogram (+ W3 frag prep blk0, + eattr->bf16 convert) -------
__global__ void k_bhist(const int* __restrict__ dst, unsigned* __restrict__ histG,
                        const float* __restrict__ W3, const float* __restrict__ b3,
                        uint4* __restrict__ w3tab, const float* __restrict__ eattr,
                        uint4* __restrict__ ea16, int E, int B, int CH) {
    __shared__ unsigned h[MAXB];
    if (blockIdx.x == 0 && threadIdx.x < 64) {
        int lane = threadIdx.x;
        int j = lane & 31, hi = lane >> 5;
#pragma unroll
        for (int s = 0; s < 3; ++s) {
            unsigned w[4];
#pragma unroll
            for (int p = 0; p < 4; ++p) {
                int k0 = s * 16 + hi * 8 + 2 * p;
                float f0 = (k0 < 40) ? W3[k0 * 32 + j] : (k0 == 40 ? b3[j] : 0.f);
                float f1 = (k0 + 1 < 40) ? W3[(k0 + 1) * 32 + j] : 0.f;
                w[p] = pk(f0, f1);
            }
            w3tab[lane * 3 + s] = uint4{w[0], w[1], w[2], w[3]};
        }
    }
    for (int t = threadIdx.x; t < B; t += blockDim.x) h[t] = 0;
    __syncthreads();
    int b = blockIdx.x;
    int beg = b * CH, end = min(E, beg + CH);
    for (int i = beg + threadIdx.x; i < end; i += blockDim.x)
        atomicAdd(&h[__builtin_nontemporal_load(dst + i) >> BSH], 1u);
    __syncthreads();
    for (int t = threadIdx.x; t < B; t += blockDim.x) histG[b * B + t] = h[t];
    // eattr fp32 -> bf16 (stream rides on idle BW of this atomic-bound kernel)
    const int T = NB * TPB;
    for (int e = blockIdx.x * blockDim.x + threadIdx.x; e < E; e += T) {
        const float4* ea = reinterpret_cast<const float4*>(eattr + (size_t)e * 8);
        float4 e0 = nt_load_f4(ea);
        float4 e1 = nt_load_f4(ea + 1);
        nt_store_u4(uint4{pk(e0.x, e0.y), pk(e0.z, e0.w),
                          pk(e1.x, e1.y), pk(e1.z, e1.w)}, ea16 + e);
    }
}

// ---- scan pass 1 (transposed read: m = bucket*NB + block) -----------------
__global__ void k_scan1t(const unsigned* __restrict__ histG, unsigned* __restrict__ bsum,
                         int M, int B) {
    __shared__ unsigned s[TPB];
    int tid = threadIdx.x;
    int i = blockIdx.x * TPB + tid;
    unsigned v = (i < M) ? histG[(i % NB) * B + (i / NB)] : 0u;
    s[tid] = v;
    __syncthreads();
    for (int ofs = TPB / 2; ofs > 0; ofs >>= 1) {
        if (tid < ofs) s[tid] += s[tid + ofs];
        __syncthreads();
    }
    if (tid == 0) bsum[blockIdx.x] = s[0];
}

// ---- scan pass 2: exclusive scan of block sums (1 block, 512 thr) ---------
__global__ void k_scan2(unsigned* __restrict__ bsum, int nb) {
    __shared__ unsigned s[512];
    int tid = threadIdx.x;
    unsigned v = (tid < nb) ? bsum[tid] : 0u;
    s[tid] = v;
    __syncthreads();
    for (int ofs = 1; ofs < 512; ofs <<= 1) {
        unsigned t = (tid >= ofs) ? s[tid - ofs] : 0u;
        __syncthreads();
        s[tid] += t;
        __syncthreads();
    }
    if (tid < nb) bsum[tid] = s[tid] - v;  // exclusive
}

// ---- scan pass 3 (transposed read): scannedM[m] ---------------------------
__global__ void k_scan3t(const unsigned* __restrict__ histG, const unsigned* __restrict__ bsum,
                         unsigned* __restrict__ scannedM, int M, int B) {
    __shared__ unsigned s[TPB];
    int tid = threadIdx.x;
    int i = blockIdx.x * TPB + tid;
    unsigned v = (i < M) ? histG[(i % NB) * B + (i / NB)] : 0u;
    s[tid] = v;
    __syncthreads();
    for (int ofs = 1; ofs < TPB; ofs <<= 1) {
        unsigned t = (tid >= ofs) ? s[tid - ofs] : 0u;
        __syncthreads();
        s[tid] += t;
        __syncthreads();
    }
    if (i < M) scannedM[i] = bsum[blockIdx.x] + s[tid] - v;
}

// ---- level-1 scatter: packed (src<<8 | dstlo) into bucket-ordered buffer --
__global__ void k_bscatter(const int* __restrict__ src, const int* __restrict__ dst,
                           const unsigned* __restrict__ scannedM, unsigned* __restrict__ lvl1,
                           int E, int B, int CH) {
    __shared__ unsigned cur[MAXB];
    int b = blockIdx.x;
    for (int t = threadIdx.x; t < B; t += blockDim.x) cur[t] = scannedM[t * NB + b];
    __syncthreads();
    int beg = b * CH, end = min(E, beg + CH);
    for (int i = beg + threadIdx.x; i < end; i += blockDim.x) {
        int d = __builtin_nontemporal_load(dst + i);
        int sv = __builtin_nontemporal_load(src + i);
        int bk = d >> BSH;
        unsigned p = atomicAdd(&cur[bk], 1u);
        lvl1[p] = ((unsigned)sv << BSH) | (unsigned)(d & ((1 << BSH) - 1));
    }
}

// ---- level-2 build: rowptr/dinv/xs + place csr_src ------------------------
__global__ void k_bbuild(const unsigned* __restrict__ lvl1, const unsigned* __restrict__ scannedM,
                         const float* __restrict__ x, unsigned* __restrict__ rowptr,
                         float* __restrict__ dinv, uint4* __restrict__ xs,
                         int* __restrict__ csr_src, int N, int E, int B) {
    __shared__ unsigned cnt[1 << BSH];
    __shared__ unsigned ro[1 << BSH];
    int b = blockIdx.x;
    int tid = threadIdx.x;
    unsigned gbase = scannedM[(size_t)b * NB];
    unsigned gend = (b + 1 < B) ? scannedM[(size_t)(b + 1) * NB] : (unsigned)E;
    cnt[tid] = 0;
    __syncthreads();
    for (unsigned i = gbase + tid; i < gend; i += (unsigned)blockDim.x)
        atomicAdd(&cnt[lvl1[i] & ((1u << BSH) - 1u)], 1u);
    __syncthreads();
    unsigned v = cnt[tid];
    ro[tid] = v;
    __syncthreads();
    for (int ofs = 1; ofs < (1 << BSH); ofs <<= 1) {
        unsigned t = (tid >= ofs) ? ro[tid - ofs] : 0u;
        __syncthreads();
        ro[tid] += t;
        __syncthreads();
    }
    unsigned excl = ro[tid] - v;  // exclusive within bucket
    int n = (b << BSH) + tid;
    if (n < N) {
        rowptr[n] = gbase + excl;
        float di = rsqrtf((float)v + 1.0f);
        dinv[n] = di;
        const float* xr = x + (size_t)n * 6;
        uint4 o;
        o.x = pk(xr[0] * di, xr[1] * di);
        o.y = pk(xr[2] * di, xr[3] * di);
        o.z = pk(xr[4] * di, xr[5] * di);
        o.w = 0u;
        xs[n] = o;
        if (n == N - 1) rowptr[N] = gend;
    }
    __syncthreads();
    cnt[tid] = gbase + excl;  // absolute write cursor
    __syncthreads();
    for (unsigned i = gbase + tid; i < gend; i += (unsigned)blockDim.x) {
        unsigned w = lvl1[i];
        unsigned p = atomicAdd(&cnt[w & ((1u << BSH) - 1u)], 1u);
        csr_src[p] = (int)(w >> BSH);
    }
}

// ---- layer-1: aggregate (8 lanes/node, batch-4 gather) + W1 + relu + W2 ---
__global__ void k_gagg6f(const unsigned* __restrict__ rowptr, const int* __restrict__ csr_src,
                         const float* __restrict__ dinv, const uint4* __restrict__ xs,
                         const float* __restrict__ W1, const float* __restrict__ b1,
                         const float* __restrict__ W2, unsigned* __restrict__ hs2w, int N) {
    int gid = blockIdx.x * blockDim.x + threadIdx.x;
    int n = gid >> 3, q = gid & 7;
    if (n >= N) return;
    unsigned beg = rowptr[n], end = rowptr[n + 1];
    float acc[6] = {0.f, 0.f, 0.f, 0.f, 0.f, 0.f};
    unsigned j = beg + q;
    while (j < end) {
        auto cidx = [&](unsigned jj) {
            return csr_src[jj < end ? jj : end - 1];  // cached: gagg16 re-reads
        };
        int i0 = cidx(j), i1 = cidx(j + 8), i2 = cidx(j + 16), i3 = cidx(j + 24);
        uint4 g0 = xs[i0];
        uint4 g1 = xs[i1];
        uint4 g2 = xs[i2];
        uint4 g3 = xs[i3];
        float t[6];
        unp6(g0, t);
#pragma unroll
        for (int i = 0; i < 6; ++i) acc[i] += t[i];
        if (j + 8 < end) {
            unp6(g1, t);
#pragma unroll
            for (int i = 0; i < 6; ++i) acc[i] += t[i];
        }
        if (j + 16 < end) {
            unp6(g2, t);
#pragma unroll
            for (int i = 0; i < 6; ++i) acc[i] += t[i];
        }
        if (j + 24 < end) {
            unp6(g3, t);
#pragma unroll
            for (int i = 0; i < 6; ++i) acc[i] += t[i];
        }
        j += 32;
    }
#pragma unroll
    for (int i = 0; i < 6; ++i) {
        acc[i] += __shfl_xor(acc[i], 1);
        acc[i] += __shfl_xor(acc[i], 2);
        acc[i] += __shfl_xor(acc[i], 4);
    }
    float t6[6];
    unp6(xs[n], t6);  // self-loop term
#pragma unroll
    for (int i = 0; i < 6; ++i) acc[i] += t6[i];
    float di = dinv[n];
    // all 32 h1 channels (redundant across lanes; VALU is cheap here)
    float h1[32];
#pragma unroll
    for (int oc = 0; oc < 32; ++oc) {
        float s = 0.f;
#pragma unroll
        for (int k = 0; k < 6; ++k) s = fmaf(acc[k], W1[k * 32 + oc], s);
        h1[oc] = fmaxf(fmaf(s, di, b1[oc]), 0.f);
    }
    // this lane's 2 output channels of the W2 GEMV (j = 2q, 2q+1)
    int j0c = 2 * q;
    float z0 = 0.f, z1 = 0.f;
#pragma unroll
    for (int c = 0; c < 32; ++c) {
        z0 = fmaf(h1[c], W2[c * 16 + j0c], z0);
        z1 = fmaf(h1[c], W2[c * 16 + j0c + 1], z1);
    }
    __builtin_nontemporal_store(pk(z0 * di, z1 * di), hs2w + (size_t)n * 8 + q);
}

// ---- layer-2 aggregate, 16 lanes/node (edge-eighth x ch-half, batch-4) ----
__global__ void k_gagg16(const unsigned* __restrict__ rowptr, const int* __restrict__ csr_src,
                         const float* __restrict__ dinv, const uint4* __restrict__ hs2,
                         const float* __restrict__ b2, uint4* __restrict__ h2, int N) {
    int gid = blockIdx.x * blockDim.x + threadIdx.x;
    int n = gid >> 4, q = gid & 15;
    int h = q & 1, e8 = q >> 1;
    if (n >= N) return;
    unsigned beg = rowptr[n], end = rowptr[n + 1];
    float acc[8] = {0.f, 0.f, 0.f, 0.f, 0.f, 0.f, 0.f, 0.f};
    unsigned j = beg + e8;
    while (j < end) {
        auto cidx = [&](unsigned jj) {
            return __builtin_nontemporal_load(csr_src + (jj < end ? jj : end - 1));
        };
        int i0 = cidx(j), i1 = cidx(j + 8), i2 = cidx(j + 16), i3 = cidx(j + 24);
        uint4 g0 = hs2[(size_t)i0 * 2 + h];
        uint4 g1 = hs2[(size_t)i1 * 2 + h];
        uint4 g2 = hs2[(size_t)i2 * 2 + h];
        uint4 g3 = hs2[(size_t)i3 * 2 + h];
        float t[8];
        unp8(g0, t);
#pragma unroll
        for (int i = 0; i < 8; ++i) acc[i] += t[i];
        if (j + 8 < end) {
            unp8(g1, t);
#pragma unroll
            for (int i = 0; i < 8; ++i) acc[i] += t[i];
        }
        if (j + 16 < end) {
            unp8(g2, t);
#pragma unroll
            for (int i = 0; i < 8; ++i) acc[i] += t[i];
        }
        if (j + 24 < end) {
            unp8(g3, t);
#pragma unroll
            for (int i = 0; i < 8; ++i) acc[i] += t[i];
        }
        j += 32;
    }
#pragma unroll
    for (int i = 0; i < 8; ++i) {
        acc[i] += __shfl_xor(acc[i], 2);
        acc[i] += __shfl_xor(acc[i], 4);
        acc[i] += __shfl_xor(acc[i], 8);
    }
    if (e8) return;
    float t8[8];
    unp8(hs2[(size_t)n * 2 + h], t8);  // self-loop term
    float di = dinv[n];
    unsigned w[4];
#pragma unroll
    for (int i = 0; i < 4; ++i) {
        float r0 = fmaxf(fmaf(acc[2 * i] + t8[2 * i], di, b2[h * 8 + 2 * i]), 0.f);
        float r1 = fmaxf(fmaf(acc[2 * i + 1] + t8[2 * i + 1], di, b2[h * 8 + 2 * i + 1]), 0.f);
        w[i] = pk(r0, r1);
    }
    h2[(size_t)n * 2 + h] = uint4{w[0], w[1], w[2], w[3]};  // hot table: normal store
}

// ---- edge MLP via 32x32x16 MFMA: 2 tiles/wave, ALL loads upfront ----------
// eattr pre-converted to bf16 (ea16): one uint4 load per edge, no pk.
__global__ void __launch_bounds__(TPB) k_edge_mfma(
    const int* __restrict__ src, const int* __restrict__ dst,
    const uint4* __restrict__ h2, const uint4* __restrict__ ea16,
    const uint4* __restrict__ w3tab, const float* __restrict__ W4,
    const float* __restrict__ b4, float* __restrict__ out, int E) {
    const int lane = threadIdx.x & 63;
    const int wave = threadIdx.x >> 6;
    const int e31 = lane & 31;
    const int hi = lane >> 5;

    short8 wA0, wA1, wA2;
    {
        const uint4* wt = w3tab + (size_t)lane * 3;
        wA0 = __builtin_bit_cast(short8, wt[0]);
        wA1 = __builtin_bit_cast(short8, wt[1]);
        wA2 = __builtin_bit_cast(short8, wt[2]);
    }
    const float4* W4v = reinterpret_cast<const float4*>(W4);
    const float4 w4q0 = W4v[hi], w4q1 = W4v[2 + hi], w4q2 = W4v[4 + hi], w4q3 = W4v[6 + hi];
    const float b4v = b4[0];
    const long base0 = ((long)blockIdx.x * 4 + wave) * 64L;  // 2 tiles x 32 edges

    const uint4 one_u = (hi == 1) ? uint4{0x3F80u, 0u, 0u, 0u} : uint4{0u, 0u, 0u, 0u};
    const short8 one_s8 = __builtin_bit_cast(short8, one_u);

    auto eclamp = [&](int it) -> size_t {
        long et = base0 + (long)it * 32 + e31;
        return (size_t)(et < E ? et : (long)(E - 1));
    };
    auto load_a2 = [&](int it) -> short8 {
        if (hi != 0) return one_s8;
        return __builtin_bit_cast(short8, nt_load_u4(ea16 + eclamp(it)));
    };

    // ALL loads upfront: 4 idx, then 4 h2 gathers + 2 ea16 loads
    int is0 = __builtin_nontemporal_load(src + eclamp(0));
    int id0 = __builtin_nontemporal_load(dst + eclamp(0));
    int is1 = __builtin_nontemporal_load(src + eclamp(1));
    int id1 = __builtin_nontemporal_load(dst + eclamp(1));
    uint4 hs0 = h2[(size_t)is0 * 2 + hi], hd0 = h2[(size_t)id0 * 2 + hi];
    uint4 hs1 = h2[(size_t)is1 * 2 + hi], hd1 = h2[(size_t)id1 * 2 + hi];
    short8 a20 = load_a2(0);
    short8 a21 = load_a2(1);

    auto tile = [&](uint4 hs, uint4 hd, short8 a2, int it) {
        f32x16 cA, cB;
#pragma unroll
        for (int i = 0; i < 16; ++i) { cA[i] = 0.f; cB[i] = 0.f; }
        cA = __builtin_amdgcn_mfma_f32_32x32x16_bf16(wA0, __builtin_bit_cast(short8, hs), cA, 0, 0, 0);
        cB = __builtin_amdgcn_mfma_f32_32x32x16_bf16(wA2, a2, cB, 0, 0, 0);
        cA = __builtin_amdgcn_mfma_f32_32x32x16_bf16(wA1, __builtin_bit_cast(short8, hd), cA, 0, 0, 0);
        float z = 0.f;
#pragma unroll
        for (int r = 0; r < 4; ++r) {
            z = fmaf(fmaxf(cA[0 * 4 + r] + cB[0 * 4 + r], 0.f), ((const float*)&w4q0)[r], z);
            z = fmaf(fmaxf(cA[1 * 4 + r] + cB[1 * 4 + r], 0.f), ((const float*)&w4q1)[r], z);
            z = fmaf(fmaxf(cA[2 * 4 + r] + cB[2 * 4 + r], 0.f), ((const float*)&w4q2)[r], z);
            z = fmaf(fmaxf(cA[3 * 4 + r] + cB[3 * 4 + r], 0.f), ((const float*)&w4q3)[r], z);
        }
        z += __shfl_xor(z, 32);
        long erow = base0 + (long)it * 32 + e31;
        if (hi == 0 && erow < E) __builtin_nontemporal_store(z + b4v, out + erow);
    };
    tile(hs0, hd0, a20, 0);
    tile(hs1, hd1, a21, 1);
}

extern "C" void kernel_launch(void* const* d_in, const int* in_sizes, int n_in,
                              void* d_out, int out_size, void* d_ws, size_t ws_size,
                              hipStream_t stream) {
    const float* x     = (const float*)d_in[0];
    const int*   ei    = (const int*)d_in[1];
    const float* eattr = (const float*)d_in[2];
    const float* W1 = (const float*)d_in[3];
    const float* b1 = (const float*)d_in[4];
    const float* W2 = (const float*)d_in[5];
    const float* b2 = (const float*)d_in[6];
    const float* W3 = (const float*)d_in[7];
    const float* b3 = (const float*)d_in[8];
    const float* W4 = (const float*)d_in[9];
    const float* b4 = (const float*)d_in[10];
    float* out = (float*)d_out;

    const int N = in_sizes[0] / 6;     // 100000
    const int E = in_sizes[2] / 8;     // 1600000
    const int* src = ei;
    const int* dst = ei + E;

    const int B  = (N + (1 << BSH) - 1) >> BSH;        // 391 buckets
    const int CH = (E + NB - 1) / NB;                  // 6250 edges/block
    const int M  = B * NB;                             // 100096
    const int nbM = (M + TPB - 1) / TPB;               // 392 (<=512)

    // workspace layout (regions 16B-aligned)
    char* wsb = (char*)d_ws;
    size_t off = 0;
    auto alloc4 = [&](size_t elems) {
        void* p = wsb + off;
        off += ((elems * 4 + 15) & ~(size_t)15);
        return p;
    };
    unsigned* rowptr   = (unsigned*)alloc4(N + 1);
    float*    dinv     = (float*)alloc4(N);
    unsigned* bsum     = (unsigned*)alloc4(512);
    unsigned* histG    = (unsigned*)alloc4((size_t)NB * B);
    unsigned* scannedM = (unsigned*)alloc4((size_t)NB * B);
    int*      csr_src  = (int*)alloc4(E);
    unsigned* big      = (unsigned*)alloc4((size_t)N * 16 > (size_t)E ? (size_t)N * 16 : (size_t)E);
    uint4*    xs       = (uint4*)alloc4((size_t)N * 4);    // [N] bf16 6ch+pad
    uint4*    w3tab    = (uint4*)alloc4(64 * 3 * 4);       // 3 KB fragment table
    uint4*    ea16     = (uint4*)alloc4((size_t)E * 4);    // [E] bf16 8ch (25.6MB)

    unsigned* lvl1 = big;                            // E u32 (dead after k_bbuild)
    uint4*    hs2  = (uint4*)big;                    // [N][2] bf16 16ch
    uint4*    h2   = (uint4*)(big + (size_t)N * 8);  // [N][2] bf16 16ch

    // bucket sort -> rowptr/dinv/xs/csr_src (w3tab + ea16 prep in bhist)
    k_bhist   <<<NB, TPB, 0, stream>>>(dst, histG, W3, b3, w3tab, eattr, ea16, E, B, CH);
    k_scan1t  <<<nbM, TPB, 0, stream>>>(histG, bsum, M, B);
    k_scan2   <<<1, 512, 0, stream>>>(bsum, nbM);
    k_scan3t  <<<nbM, TPB, 0, stream>>>(histG, bsum, scannedM, M, B);
    k_bscatter<<<NB, TPB, 0, stream>>>(src, dst, scannedM, lvl1, E, B, CH);
    k_bbuild  <<<B, 1 << BSH, 0, stream>>>(lvl1, scannedM, x, rowptr, dinv, xs, csr_src, N, E, B);

    // GCN layer 1 (aggregate + W1 + relu + W2 fused; 8 lanes/node)
    k_gagg6f<<<((size_t)N * 8 + TPB - 1) / TPB, TPB, 0, stream>>>(
        rowptr, csr_src, dinv, xs, W1, b1, W2, (unsigned*)hs2, N);

    // GCN layer 2 (16 lanes/node aggregate)
    k_gagg16<<<((size_t)N * 16 + TPB - 1) / TPB, TPB, 0, stream>>>(
        rowptr, csr_src, dinv, hs2, b2, h2, N);

    // edge MLP (MFMA 32x32): 4 waves/block, 64 edges per wave
    const int eblocks = (E + 255) / 256;  // 6250
    k_edge_mfma<<<eblocks, TPB, 0, stream>>>(src, dst, (const uint4*)h2, ea16,
                                             (const uint4*)w3tab, W4, b4, out, E);
}

// Round 23
// 142.656 us; speedup vs baseline: 1.0846x; 1.0846x over previous
//
#include <hip/hip_runtime.h>

// EdgeWeightPredictor: 2-layer GCN (sym-norm, self-loops) + edge MLP.
// N=100000 nodes (IN_CH=6), E=1600000 edges (EDGE_FEAT=8).
// Round 23 = exact revert to R21 (142.8us best). R22's eattr->bf16
// pre-convert ADDED net traffic (51->102MB): convert stream cost ~13us in
// k_bhist vs only ~5us saved in k_edge. Reverted.

constexpr int TPB = 256;
constexpr int NB = 256;         // level-1 blocks
constexpr int BSH = 8;          // 256 nodes per bucket
constexpr int MAXB = 1024;      // max buckets supported (N <= 262144)

using short8  = __attribute__((ext_vector_type(8))) short;
using f32x16  = __attribute__((ext_vector_type(16))) float;
using uintx4  = __attribute__((ext_vector_type(4))) unsigned;
using floatx4 = __attribute__((ext_vector_type(4))) float;

__device__ __forceinline__ float4 nt_load_f4(const float4* p) {
    floatx4 e = __builtin_nontemporal_load(reinterpret_cast<const floatx4*>(p));
    return float4{e.x, e.y, e.z, e.w};
}

// ---- bf16 pack/unpack (RTNE) ----------------------------------------------
__device__ __forceinline__ float bf_lo(unsigned w) {
    return __builtin_bit_cast(float, (unsigned)(w << 16));
}
__device__ __forceinline__ float bf_hi(unsigned w) {
    return __builtin_bit_cast(float, w & 0xFFFF0000u);
}
__device__ __forceinline__ unsigned bf1(float f) {
    unsigned u = __builtin_bit_cast(unsigned, f);
    return (u + 0x7FFFu + ((u >> 16) & 1u)) >> 16;
}
__device__ __forceinline__ unsigned pk(float lo, float hi) {
    return bf1(lo) | (bf1(hi) << 16);
}
__device__ __forceinline__ void unp8(uint4 v, float* o) {
    o[0] = bf_lo(v.x); o[1] = bf_hi(v.x); o[2] = bf_lo(v.y); o[3] = bf_hi(v.y);
    o[4] = bf_lo(v.z); o[5] = bf_hi(v.z); o[6] = bf_lo(v.w); o[7] = bf_hi(v.w);
}
__device__ __forceinline__ void unp6(uint4 v, float* o) {
    o[0] = bf_lo(v.x); o[1] = bf_hi(v.x); o[2] = bf_lo(v.y); o[3] = bf_hi(v.y);
    o[4] = bf_lo(v.z); o[5] = bf_hi(v.z);
}

// ---- level-1 histogram (+ W3 fragment prep on block 0) --------------------
__global__ void k_bhist(const int* __restrict__ dst, unsigned* __restrict__ histG,
                        const float* __restrict__ W3, const float* __restrict__ b3,
                        uint4* __restrict__ w3tab, int E, int B, int CH) {
    __shared__ unsigned h[MAXB];
    if (blockIdx.x == 0 && threadIdx.x < 64) {
        int lane = threadIdx.x;
        int j = lane & 31, hi = lane >> 5;
#pragma unroll
        for (int s = 0; s < 3; ++s) {
            unsigned w[4];
#pragma unroll
            for (int p = 0; p < 4; ++p) {
                int k0 = s * 16 + hi * 8 + 2 * p;
                float f0 = (k0 < 40) ? W3[k0 * 32 + j] : (k0 == 40 ? b3[j] : 0.f);
                float f1 = (k0 + 1 < 40) ? W3[(k0 + 1) * 32 + j] : 0.f;
                w[p] = pk(f0, f1);
            }
            w3tab[lane * 3 + s] = uint4{w[0], w[1], w[2], w[3]};
        }
    }
    for (int t = threadIdx.x; t < B; t += blockDim.x) h[t] = 0;
    __syncthreads();
    int b = blockIdx.x;
    int beg = b * CH, end = min(E, beg + CH);
    for (int i = beg + threadIdx.x; i < end; i += blockDim.x)
        atomicAdd(&h[__builtin_nontemporal_load(dst + i) >> BSH], 1u);
    __syncthreads();
    for (int t = threadIdx.x; t < B; t += blockDim.x) histG[b * B + t] = h[t];
}

// ---- scan pass 1 (transposed read: m = bucket*NB + block) -----------------
__global__ void k_scan1t(const unsigned* __restrict__ histG, unsigned* __restrict__ bsum,
                         int M, int B) {
    __shared__ unsigned s[TPB];
    int tid = threadIdx.x;
    int i = blockIdx.x * TPB + tid;
    unsigned v = (i < M) ? histG[(i % NB) * B + (i / NB)] : 0u;
    s[tid] = v;
    __syncthreads();
    for (int ofs = TPB / 2; ofs > 0; ofs >>= 1) {
        if (tid < ofs) s[tid] += s[tid + ofs];
        __syncthreads();
    }
    if (tid == 0) bsum[blockIdx.x] = s[0];
}

// ---- scan pass 2: exclusive scan of block sums (1 block, 512 thr) ---------
__global__ void k_scan2(unsigned* __restrict__ bsum, int nb) {
    __shared__ unsigned s[512];
    int tid = threadIdx.x;
    unsigned v = (tid < nb) ? bsum[tid] : 0u;
    s[tid] = v;
    __syncthreads();
    for (int ofs = 1; ofs < 512; ofs <<= 1) {
        unsigned t = (tid >= ofs) ? s[tid - ofs] : 0u;
        __syncthreads();
        s[tid] += t;
        __syncthreads();
    }
    if (tid < nb) bsum[tid] = s[tid] - v;  // exclusive
}

// ---- scan pass 3 (transposed read): scannedM[m] ---------------------------
__global__ void k_scan3t(const unsigned* __restrict__ histG, const unsigned* __restrict__ bsum,
                         unsigned* __restrict__ scannedM, int M, int B) {
    __shared__ unsigned s[TPB];
    int tid = threadIdx.x;
    int i = blockIdx.x * TPB + tid;
    unsigned v = (i < M) ? histG[(i % NB) * B + (i / NB)] : 0u;
    s[tid] = v;
    __syncthreads();
    for (int ofs = 1; ofs < TPB; ofs <<= 1) {
        unsigned t = (tid >= ofs) ? s[tid - ofs] : 0u;
        __syncthreads();
        s[tid] += t;
        __syncthreads();
    }
    if (i < M) scannedM[i] = bsum[blockIdx.x] + s[tid] - v;
}

// ---- level-1 scatter: packed (src<<8 | dstlo) into bucket-ordered buffer --
__global__ void k_bscatter(const int* __restrict__ src, const int* __restrict__ dst,
                           const unsigned* __restrict__ scannedM, unsigned* __restrict__ lvl1,
                           int E, int B, int CH) {
    __shared__ unsigned cur[MAXB];
    int b = blockIdx.x;
    for (int t = threadIdx.x; t < B; t += blockDim.x) cur[t] = scannedM[t * NB + b];
    __syncthreads();
    int beg = b * CH, end = min(E, beg + CH);
    for (int i = beg + threadIdx.x; i < end; i += blockDim.x) {
        int d = __builtin_nontemporal_load(dst + i);
        int sv = __builtin_nontemporal_load(src + i);
        int bk = d >> BSH;
        unsigned p = atomicAdd(&cur[bk], 1u);
        lvl1[p] = ((unsigned)sv << BSH) | (unsigned)(d & ((1 << BSH) - 1));
    }
}

// ---- level-2 build: rowptr/dinv/xs + place csr_src ------------------------
__global__ void k_bbuild(const unsigned* __restrict__ lvl1, const unsigned* __restrict__ scannedM,
                         const float* __restrict__ x, unsigned* __restrict__ rowptr,
                         float* __restrict__ dinv, uint4* __restrict__ xs,
                         int* __restrict__ csr_src, int N, int E, int B) {
    __shared__ unsigned cnt[1 << BSH];
    __shared__ unsigned ro[1 << BSH];
    int b = blockIdx.x;
    int tid = threadIdx.x;
    unsigned gbase = scannedM[(size_t)b * NB];
    unsigned gend = (b + 1 < B) ? scannedM[(size_t)(b + 1) * NB] : (unsigned)E;
    cnt[tid] = 0;
    __syncthreads();
    for (unsigned i = gbase + tid; i < gend; i += (unsigned)blockDim.x)
        atomicAdd(&cnt[lvl1[i] & ((1u << BSH) - 1u)], 1u);
    __syncthreads();
    unsigned v = cnt[tid];
    ro[tid] = v;
    __syncthreads();
    for (int ofs = 1; ofs < (1 << BSH); ofs <<= 1) {
        unsigned t = (tid >= ofs) ? ro[tid - ofs] : 0u;
        __syncthreads();
        ro[tid] += t;
        __syncthreads();
    }
    unsigned excl = ro[tid] - v;  // exclusive within bucket
    int n = (b << BSH) + tid;
    if (n < N) {
        rowptr[n] = gbase + excl;
        float di = rsqrtf((float)v + 1.0f);
        dinv[n] = di;
        const float* xr = x + (size_t)n * 6;
        uint4 o;
        o.x = pk(xr[0] * di, xr[1] * di);
        o.y = pk(xr[2] * di, xr[3] * di);
        o.z = pk(xr[4] * di, xr[5] * di);
        o.w = 0u;
        xs[n] = o;
        if (n == N - 1) rowptr[N] = gend;
    }
    __syncthreads();
    cnt[tid] = gbase + excl;  // absolute write cursor
    __syncthreads();
    for (unsigned i = gbase + tid; i < gend; i += (unsigned)blockDim.x) {
        unsigned w = lvl1[i];
        unsigned p = atomicAdd(&cnt[w & ((1u << BSH) - 1u)], 1u);
        csr_src[p] = (int)(w >> BSH);
    }
}

// ---- layer-1: aggregate (8 lanes/node, batch-4 gather) + W1 + relu + W2 ---
__global__ void k_gagg6f(const unsigned* __restrict__ rowptr, const int* __restrict__ csr_src,
                         const float* __restrict__ dinv, const uint4* __restrict__ xs,
                         const float* __restrict__ W1, const float* __restrict__ b1,
                         const float* __restrict__ W2, unsigned* __restrict__ hs2w, int N) {
    int gid = blockIdx.x * blockDim.x + threadIdx.x;
    int n = gid >> 3, q = gid & 7;
    if (n >= N) return;
    unsigned beg = rowptr[n], end = rowptr[n + 1];
    float acc[6] = {0.f, 0.f, 0.f, 0.f, 0.f, 0.f};
    unsigned j = beg + q;
    while (j < end) {
        auto cidx = [&](unsigned jj) {
            return csr_src[jj < end ? jj : end - 1];  // cached: gagg16 re-reads
        };
        int i0 = cidx(j), i1 = cidx(j + 8), i2 = cidx(j + 16), i3 = cidx(j + 24);
        uint4 g0 = xs[i0];
        uint4 g1 = xs[i1];
        uint4 g2 = xs[i2];
        uint4 g3 = xs[i3];
        float t[6];
        unp6(g0, t);
#pragma unroll
        for (int i = 0; i < 6; ++i) acc[i] += t[i];
        if (j + 8 < end) {
            unp6(g1, t);
#pragma unroll
            for (int i = 0; i < 6; ++i) acc[i] += t[i];
        }
        if (j + 16 < end) {
            unp6(g2, t);
#pragma unroll
            for (int i = 0; i < 6; ++i) acc[i] += t[i];
        }
        if (j + 24 < end) {
            unp6(g3, t);
#pragma unroll
            for (int i = 0; i < 6; ++i) acc[i] += t[i];
        }
        j += 32;
    }
#pragma unroll
    for (int i = 0; i < 6; ++i) {
        acc[i] += __shfl_xor(acc[i], 1);
        acc[i] += __shfl_xor(acc[i], 2);
        acc[i] += __shfl_xor(acc[i], 4);
    }
    float t6[6];
    unp6(xs[n], t6);  // self-loop term
#pragma unroll
    for (int i = 0; i < 6; ++i) acc[i] += t6[i];
    float di = dinv[n];
    // all 32 h1 channels (redundant across lanes; VALU is cheap here)
    float h1[32];
#pragma unroll
    for (int oc = 0; oc < 32; ++oc) {
        float s = 0.f;
#pragma unroll
        for (int k = 0; k < 6; ++k) s = fmaf(acc[k], W1[k * 32 + oc], s);
        h1[oc] = fmaxf(fmaf(s, di, b1[oc]), 0.f);
    }
    // this lane's 2 output channels of the W2 GEMV (j = 2q, 2q+1)
    int j0c = 2 * q;
    float z0 = 0.f, z1 = 0.f;
#pragma unroll
    for (int c = 0; c < 32; ++c) {
        z0 = fmaf(h1[c], W2[c * 16 + j0c], z0);
        z1 = fmaf(h1[c], W2[c * 16 + j0c + 1], z1);
    }
    __builtin_nontemporal_store(pk(z0 * di, z1 * di), hs2w + (size_t)n * 8 + q);
}

// ---- layer-2 aggregate, 16 lanes/node (edge-eighth x ch-half, batch-4) ----
__global__ void k_gagg16(const unsigned* __restrict__ rowptr, const int* __restrict__ csr_src,
                         const float* __restrict__ dinv, const uint4* __restrict__ hs2,
                         const float* __restrict__ b2, uint4* __restrict__ h2, int N) {
    int gid = blockIdx.x * blockDim.x + threadIdx.x;
    int n = gid >> 4, q = gid & 15;
    int h = q & 1, e8 = q >> 1;
    if (n >= N) return;
    unsigned beg = rowptr[n], end = rowptr[n + 1];
    float acc[8] = {0.f, 0.f, 0.f, 0.f, 0.f, 0.f, 0.f, 0.f};
    unsigned j = beg + e8;
    while (j < end) {
        auto cidx = [&](unsigned jj) {
            return __builtin_nontemporal_load(csr_src + (jj < end ? jj : end - 1));
        };
        int i0 = cidx(j), i1 = cidx(j + 8), i2 = cidx(j + 16), i3 = cidx(j + 24);
        uint4 g0 = hs2[(size_t)i0 * 2 + h];
        uint4 g1 = hs2[(size_t)i1 * 2 + h];
        uint4 g2 = hs2[(size_t)i2 * 2 + h];
        uint4 g3 = hs2[(size_t)i3 * 2 + h];
        float t[8];
        unp8(g0, t);
#pragma unroll
        for (int i = 0; i < 8; ++i) acc[i] += t[i];
        if (j + 8 < end) {
            unp8(g1, t);
#pragma unroll
            for (int i = 0; i < 8; ++i) acc[i] += t[i];
        }
        if (j + 16 < end) {
            unp8(g2, t);
#pragma unroll
            for (int i = 0; i < 8; ++i) acc[i] += t[i];
        }
        if (j + 24 < end) {
            unp8(g3, t);
#pragma unroll
            for (int i = 0; i < 8; ++i) acc[i] += t[i];
        }
        j += 32;
    }
#pragma unroll
    for (int i = 0; i < 8; ++i) {
        acc[i] += __shfl_xor(acc[i], 2);
        acc[i] += __shfl_xor(acc[i], 4);
        acc[i] += __shfl_xor(acc[i], 8);
    }
    if (e8) return;
    float t8[8];
    unp8(hs2[(size_t)n * 2 + h], t8);  // self-loop term
    float di = dinv[n];
    unsigned w[4];
#pragma unroll
    for (int i = 0; i < 4; ++i) {
        float r0 = fmaxf(fmaf(acc[2 * i] + t8[2 * i], di, b2[h * 8 + 2 * i]), 0.f);
        float r1 = fmaxf(fmaf(acc[2 * i + 1] + t8[2 * i + 1], di, b2[h * 8 + 2 * i + 1]), 0.f);
        w[i] = pk(r0, r1);
    }
    h2[(size_t)n * 2 + h] = uint4{w[0], w[1], w[2], w[3]};  // hot table: normal store
}

// ---- edge MLP via 32x32x16 MFMA: 2 tiles/wave, ALL loads upfront ----------
// Split accumulators: cA (h2[src], h2[dst] serial) + cB (eattr) independent;
// c = cA + cB before relu (algebraically identical).
__global__ void __launch_bounds__(TPB) k_edge_mfma(
    const int* __restrict__ src, const int* __restrict__ dst,
    const uint4* __restrict__ h2, const float* __restrict__ eattr,
    const uint4* __restrict__ w3tab, const float* __restrict__ W4,
    const float* __restrict__ b4, float* __restrict__ out, int E) {
    const int lane = threadIdx.x & 63;
    const int wave = threadIdx.x >> 6;
    const int e31 = lane & 31;
    const int hi = lane >> 5;

    short8 wA0, wA1, wA2;
    {
        const uint4* wt = w3tab + (size_t)lane * 3;
        wA0 = __builtin_bit_cast(short8, wt[0]);
        wA1 = __builtin_bit_cast(short8, wt[1]);
        wA2 = __builtin_bit_cast(short8, wt[2]);
    }
    const float4* W4v = reinterpret_cast<const float4*>(W4);
    const float4 w4q0 = W4v[hi], w4q1 = W4v[2 + hi], w4q2 = W4v[4 + hi], w4q3 = W4v[6 + hi];
    const float b4v = b4[0];
    const long base0 = ((long)blockIdx.x * 4 + wave) * 64L;  // 2 tiles x 32 edges

    const uint4 one_u = (hi == 1) ? uint4{0x3F80u, 0u, 0u, 0u} : uint4{0u, 0u, 0u, 0u};
    const short8 one_s8 = __builtin_bit_cast(short8, one_u);

    auto eclamp = [&](int it) -> size_t {
        long et = base0 + (long)it * 32 + e31;
        return (size_t)(et < E ? et : (long)(E - 1));
    };
    auto load_a2 = [&](int it) -> short8 {
        if (hi != 0) return one_s8;
        const float4* ea = reinterpret_cast<const float4*>(eattr + eclamp(it) * 8);
        float4 e0 = nt_load_f4(ea);
        float4 e1 = nt_load_f4(ea + 1);
        return __builtin_bit_cast(short8, uint4{pk(e0.x, e0.y), pk(e0.z, e0.w),
                                                pk(e1.x, e1.y), pk(e1.z, e1.w)});
    };

    // ALL loads upfront: 4 idx, then 4 h2 gathers + 2 eattr loads
    int is0 = __builtin_nontemporal_load(src + eclamp(0));
    int id0 = __builtin_nontemporal_load(dst + eclamp(0));
    int is1 = __builtin_nontemporal_load(src + eclamp(1));
    int id1 = __builtin_nontemporal_load(dst + eclamp(1));
    uint4 hs0 = h2[(size_t)is0 * 2 + hi], hd0 = h2[(size_t)id0 * 2 + hi];
    uint4 hs1 = h2[(size_t)is1 * 2 + hi], hd1 = h2[(size_t)id1 * 2 + hi];
    short8 a20 = load_a2(0);
    short8 a21 = load_a2(1);

    auto tile = [&](uint4 hs, uint4 hd, short8 a2, int it) {
        f32x16 cA, cB;
#pragma unroll
        for (int i = 0; i < 16; ++i) { cA[i] = 0.f; cB[i] = 0.f; }
        cA = __builtin_amdgcn_mfma_f32_32x32x16_bf16(wA0, __builtin_bit_cast(short8, hs), cA, 0, 0, 0);
        cB = __builtin_amdgcn_mfma_f32_32x32x16_bf16(wA2, a2, cB, 0, 0, 0);
        cA = __builtin_amdgcn_mfma_f32_32x32x16_bf16(wA1, __builtin_bit_cast(short8, hd), cA, 0, 0, 0);
        float z = 0.f;
#pragma unroll
        for (int r = 0; r < 4; ++r) {
            z = fmaf(fmaxf(cA[0 * 4 + r] + cB[0 * 4 + r], 0.f), ((const float*)&w4q0)[r], z);
            z = fmaf(fmaxf(cA[1 * 4 + r] + cB[1 * 4 + r], 0.f), ((const float*)&w4q1)[r], z);
            z = fmaf(fmaxf(cA[2 * 4 + r] + cB[2 * 4 + r], 0.f), ((const float*)&w4q2)[r], z);
            z = fmaf(fmaxf(cA[3 * 4 + r] + cB[3 * 4 + r], 0.f), ((const float*)&w4q3)[r], z);
        }
        z += __shfl_xor(z, 32);
        long erow = base0 + (long)it * 32 + e31;
        if (hi == 0 && erow < E) __builtin_nontemporal_store(z + b4v, out + erow);
    };
    tile(hs0, hd0, a20, 0);
    tile(hs1, hd1, a21, 1);
}

extern "C" void kernel_launch(void* const* d_in, const int* in_sizes, int n_in,
                              void* d_out, int out_size, void* d_ws, size_t ws_size,
                              hipStream_t stream) {
    const float* x     = (const float*)d_in[0];
    const int*   ei    = (const int*)d_in[1];
    const float* eattr = (const float*)d_in[2];
    const float* W1 = (const float*)d_in[3];
    const float* b1 = (const float*)d_in[4];
    const float* W2 = (const float*)d_in[5];
    const float* b2 = (const float*)d_in[6];
    const float* W3 = (const float*)d_in[7];
    const float* b3 = (const float*)d_in[8];
    const float* W4 = (const float*)d_in[9];
    const float* b4 = (const float*)d_in[10];
    float* out = (float*)d_out;

    const int N = in_sizes[0] / 6;     // 100000
    const int E = in_sizes[2] / 8;     // 1600000
    const int* src = ei;
    const int* dst = ei + E;

    const int B  = (N + (1 << BSH) - 1) >> BSH;        // 391 buckets
    const int CH = (E + NB - 1) / NB;                  // 6250 edges/block
    const int M  = B * NB;                             // 100096
    const int nbM = (M + TPB - 1) / TPB;               // 392 (<=512)

    // workspace layout (regions 16B-aligned)
    char* wsb = (char*)d_ws;
    size_t off = 0;
    auto alloc4 = [&](size_t elems) {
        void* p = wsb + off;
        off += ((elems * 4 + 15) & ~(size_t)15);
        return p;
    };
    unsigned* rowptr   = (unsigned*)alloc4(N + 1);
    float*    dinv     = (float*)alloc4(N);
    unsigned* bsum     = (unsigned*)alloc4(512);
    unsigned* histG    = (unsigned*)alloc4((size_t)NB * B);
    unsigned* scannedM = (unsigned*)alloc4((size_t)NB * B);
    int*      csr_src  = (int*)alloc4(E);
    unsigned* big      = (unsigned*)alloc4((size_t)N * 16 > (size_t)E ? (size_t)N * 16 : (size_t)E);
    uint4*    xs       = (uint4*)alloc4((size_t)N * 4);    // [N] bf16 6ch+pad
    uint4*    w3tab    = (uint4*)alloc4(64 * 3 * 4);       // 3 KB fragment table

    unsigned* lvl1 = big;                            // E u32 (dead after k_bbuild)
    uint4*    hs2  = (uint4*)big;                    // [N][2] bf16 16ch
    uint4*    h2   = (uint4*)(big + (size_t)N * 8);  // [N][2] bf16 16ch

    // bucket sort -> rowptr/dinv/xs/csr_src (w3tab prep piggybacks on bhist)
    k_bhist   <<<NB, TPB, 0, stream>>>(dst, histG, W3, b3, w3tab, E, B, CH);
    k_scan1t  <<<nbM, TPB, 0, stream>>>(histG, bsum, M, B);
    k_scan2   <<<1, 512, 0, stream>>>(bsum, nbM);
    k_scan3t  <<<nbM, TPB, 0, stream>>>(histG, bsum, scannedM, M, B);
    k_bscatter<<<NB, TPB, 0, stream>>>(src, dst, scannedM, lvl1, E, B, CH);
    k_bbuild  <<<B, 1 << BSH, 0, stream>>>(lvl1, scannedM, x, rowptr, dinv, xs, csr_src, N, E, B);

    // GCN layer 1 (aggregate + W1 + relu + W2 fused; 8 lanes/node)
    k_gagg6f<<<((size_t)N * 8 + TPB - 1) / TPB, TPB, 0, stream>>>(
        rowptr, csr_src, dinv, xs, W1, b1, W2, (unsigned*)hs2, N);

    // GCN layer 2 (16 lanes/node aggregate)
    k_gagg16<<<((size_t)N * 16 + TPB - 1) / TPB, TPB, 0, stream>>>(
        rowptr, csr_src, dinv, hs2, b2, h2, N);

    // edge MLP (MFMA 32x32): 4 waves/block, 64 edges per wave
    const int eblocks = (E + 255) / 256;  // 6250
    k_edge_mfma<<<eblocks, TPB, 0, stream>>>(src, dst, (const uint4*)h2, eattr,
                                             (const uint4*)w3tab, W4, b4, out, E);
}